// Round 3
// baseline (545.800 us; speedup 1.0000x reference)
//
#include <hip/hip_runtime.h>
#include <stdint.h>

typedef __bf16 bf16_t;
typedef __bf16 bf16x4 __attribute__((ext_vector_type(4)));
typedef __bf16 bf16x8 __attribute__((ext_vector_type(8)));
typedef float  f32x4  __attribute__((ext_vector_type(4)));

typedef __attribute__((address_space(1))) const uint32_t gas_u32;
typedef __attribute__((address_space(3))) uint32_t las_u32;

#define MFMA16(a, b, c) __builtin_amdgcn_mfma_f32_16x16x32_bf16((a), (b), (c), 0, 0, 0)

__device__ __forceinline__ void gl_lds16(const bf16_t* g, bf16_t* l) {
    __builtin_amdgcn_global_load_lds((gas_u32*)g, (las_u32*)l, 16, 0, 0);
}

// ---------------------------------------------------------------------------
// fp32 -> bf16 elementwise cast, 8 elem/thread.
// ---------------------------------------------------------------------------
__global__ __launch_bounds__(256) void castbf(const float* __restrict__ X,
                                              bf16_t* __restrict__ Xb)
{
    size_t i = ((size_t)blockIdx.x * 256 + threadIdx.x) * 8;
    float4 a = *(const float4*)&X[i];
    float4 b = *(const float4*)&X[i + 4];
    bf16x8 o;
    o[0] = (bf16_t)a.x; o[1] = (bf16_t)a.y; o[2] = (bf16_t)a.z; o[3] = (bf16_t)a.w;
    o[4] = (bf16_t)b.x; o[5] = (bf16_t)b.y; o[6] = (bf16_t)b.z; o[7] = (bf16_t)b.w;
    *(bf16x8*)&Xb[i] = o;
}

// ---------------------------------------------------------------------------
// Transpose+cast 1024x1024 fp32 weights -> bf16: O[c][r] = W[r][c].
// grid (16,16,4), 256 thr. WT rows 0..1023=WqT, ..2047=WkT, ..3071=WvT, ..=WoT
// ---------------------------------------------------------------------------
__global__ __launch_bounds__(256) void ktrans(
    const float* __restrict__ W0, const float* __restrict__ W1,
    const float* __restrict__ W2, const float* __restrict__ W3,
    bf16_t* __restrict__ WT)
{
    __shared__ float t[64 * 68];
    const int z = blockIdx.z;
    const float* W = (z == 0) ? W0 : (z == 1) ? W1 : (z == 2) ? W2 : W3;
    bf16_t* O = WT + (size_t)z * 1024 * 1024;
    const int r0 = blockIdx.y * 64, c0 = blockIdx.x * 64;
    const int tid = threadIdx.x;
    const int row = tid >> 2, colg = (tid & 3) * 16;
#pragma unroll
    for (int p = 0; p < 4; ++p)
        *(float4*)&t[row * 68 + colg + p * 4] =
            *(const float4*)&W[(size_t)(r0 + row) * 1024 + c0 + colg + p * 4];
    __syncthreads();
    bf16x8 v0, v1;
#pragma unroll
    for (int j = 0; j < 8; ++j) {
        v0[j] = (bf16_t)t[(colg + j) * 68 + row];
        v1[j] = (bf16_t)t[(colg + 8 + j) * 68 + row];
    }
    *(bf16x8*)&O[(size_t)(c0 + row) * 1024 + r0 + colg] = v0;
    *(bf16x8*)&O[(size_t)(c0 + row) * 1024 + r0 + colg + 8] = v1;
}

// ---------------------------------------------------------------------------
// C = A(MxK) * Bt(NxK)^T + bias, bf16 in, fp32 accum.
// AHM:  A is head-major [b(4)][h(16)][s(4096)][d(64)] (m=b*4096+s, k=h*64+d)
// CMODE 0: row-major OutT C[m*N+n] (+bias b0[n])
// CMODE 2: QKV head-major bf16: t=n>>10 selects {Q,K,V} slab (stride 16M elem),
//          h=(n>>6)&15, d=n&63; bias from {b0,b1,b2}[t][n&1023].
// ---------------------------------------------------------------------------
template <int AHM, int CMODE, typename OutT>
__global__ __launch_bounds__(256) void gemm_bt(
    const bf16_t* __restrict__ A, const bf16_t* __restrict__ Bt,
    const float* __restrict__ b0, const float* __restrict__ b1,
    const float* __restrict__ b2, OutT* __restrict__ C,
    int M, int N, int K)
{
    __shared__ bf16_t As[128 * 32];
    __shared__ bf16_t Bs[128 * 32];
    const int tid = threadIdx.x;
    const int lane = tid & 63, wave = tid >> 6;
    const int q = lane >> 4, ln = lane & 15;
    const int m0 = blockIdx.x * 128, n0 = blockIdx.y * 128;
    const int wm = (wave >> 1) * 64, wn = (wave & 1) * 64;
    const int srow = tid >> 2, scol = (tid & 3) * 8;

    f32x4 acc[4][4] = {};
    const bf16_t* Ag = A + (size_t)(m0 + srow) * K + scol;   // non-HM path
    size_t ab1 = 0;
    if (AHM) {
        int m = m0 + srow;
        ab1 = (size_t)(m >> 12) * 4194304 + (size_t)(m & 4095) * 64 + scol;
    }
    const bf16_t* Bg = Bt + (size_t)(n0 + srow) * K + scol;
    bf16_t* Al = As + srow * 32 + scol;
    bf16_t* Bl = Bs + srow * 32 + scol;

    for (int k0 = 0; k0 < K; k0 += 32) {
        __syncthreads();
        if (AHM) {
            const bf16_t* a1 = A + ab1 + (size_t)(k0 >> 6) * 262144 + (k0 & 63);
            gl_lds16(a1, Al);
            gl_lds16(a1 + 4096, Al + 64 * 32);   // +64 rows, same b
        } else {
            gl_lds16(Ag + k0, Al);
            gl_lds16(Ag + k0 + (size_t)64 * K, Al + 64 * 32);
        }
        gl_lds16(Bg + k0, Bl);
        gl_lds16(Bg + k0 + (size_t)64 * K, Bl + 64 * 32);
        __syncthreads();
        bf16x8 a[4], b[4];
#pragma unroll
        for (int mt = 0; mt < 4; ++mt)
            a[mt] = *(const bf16x8*)&As[(wm + mt * 16 + ln) * 32 + q * 8];
#pragma unroll
        for (int nt = 0; nt < 4; ++nt)
            b[nt] = *(const bf16x8*)&Bs[(wn + nt * 16 + ln) * 32 + q * 8];
#pragma unroll
        for (int mt = 0; mt < 4; ++mt)
#pragma unroll
            for (int nt = 0; nt < 4; ++nt)
                acc[mt][nt] = MFMA16(a[mt], b[nt], acc[mt][nt]);
    }

    if (CMODE == 0) {
#pragma unroll
        for (int nt = 0; nt < 4; ++nt) {
            int n = n0 + wn + nt * 16 + ln;
            float bv = b0[n];
#pragma unroll
            for (int mt = 0; mt < 4; ++mt) {
                int mb = m0 + wm + mt * 16 + q * 4;
#pragma unroll
                for (int r = 0; r < 4; ++r)
                    C[(size_t)(mb + r) * N + n] = (OutT)(acc[mt][nt][r] + bv);
            }
        }
    } else {
#pragma unroll
        for (int nt = 0; nt < 4; ++nt) {
            int n = n0 + wn + nt * 16 + ln;
            int t = n >> 10;
            const float* bp = (t == 0) ? b0 : (t == 1) ? b1 : b2;
            float bv = bp[n & 1023];
            int h = (n >> 6) & 15, d = n & 63;
#pragma unroll
            for (int mt = 0; mt < 4; ++mt) {
                int m = m0 + wm + mt * 16 + q * 4;
                int bI = m >> 12, s = m & 4095;
                bf16_t* Cp = (bf16_t*)C + (size_t)t * 16777216 +
                             (size_t)(bI * 16 + h) * 262144 + (size_t)s * 64 + d;
#pragma unroll
                for (int r = 0; r < 4; ++r)
                    Cp[(size_t)r * 64] = (bf16_t)(acc[mt][nt][r] + bv);
            }
        }
    }
}

// ---------------------------------------------------------------------------
// K-side, head-major K/V, fused L2-norm. Kp=relu(Khat*proj^T)+0.1;
// partial KV[f][n] per s-chunk of 1024. grid (64 bh, 4), 256 thr.
// P[bh][c][n(80)][f(256)] fp32. n: 0..63=d, 64=Ksum, 65..79=0.
// ---------------------------------------------------------------------------
__global__ __launch_bounds__(256) void kside(
    const bf16_t* __restrict__ Khm, const bf16_t* __restrict__ Vhm,
    const bf16_t* __restrict__ proj, float* __restrict__ P)
{
    __shared__ bf16_t KpT[256 * 72];  // [f][s], wave-private f-slices
    __shared__ bf16_t Vt[80 * 72];    // [n][s], shared
    const int tid = threadIdx.x;
    const int lane = tid & 63, wave = tid >> 6;
    const int q = lane >> 4, ln = lane & 15;
    const int bh = blockIdx.x, c = blockIdx.y;

    const bf16_t* Kh = Khm + (size_t)bh * 262144;
    const bf16_t* Vh = Vhm + (size_t)bh * 262144;
    const bf16_t* pr = proj + (size_t)(bh & 15) * 16384;

    for (int i = tid; i < 16 * 72; i += 256) {
        int rr = i / 72, cc = i % 72;
        Vt[(64 + rr) * 72 + cc] = (rr == 0) ? (bf16_t)1.0f : (bf16_t)0.0f;
    }
    bf16x8 pf[4][2];
#pragma unroll
    for (int nt = 0; nt < 4; ++nt)
#pragma unroll
        for (int ks = 0; ks < 2; ++ks)
            pf[nt][ks] = *(const bf16x8*)&pr[(size_t)(wave * 64 + nt * 16 + ln) * 64 + ks * 32 + q * 8];

    f32x4 kv[4][5] = {};
    const int s_base = c * 1024;
    for (int st = 0; st < 16; ++st) {
        const int s0 = s_base + st * 64;
        // phase 1: fused norm + features (64 s x this wave's 64 f)
        f32x4 fa[4][4] = {};
#pragma unroll
        for (int mt = 0; mt < 4; ++mt) {
            const bf16_t* rp = &Kh[(size_t)(s0 + mt * 16 + ln) * 64 + q * 8];
            bf16x8 a0 = *(const bf16x8*)rp;
            bf16x8 a1 = *(const bf16x8*)(rp + 32);
            float f[16], ss = 0.f;
#pragma unroll
            for (int i = 0; i < 8; ++i) { f[i] = (float)a0[i]; f[8 + i] = (float)a1[i]; }
#pragma unroll
            for (int i = 0; i < 16; ++i) ss += f[i] * f[i];
            ss += __shfl_xor(ss, 16, 64);
            ss += __shfl_xor(ss, 32, 64);
            float sc = 1.0f / (sqrtf(ss) + 1e-8f);
            bf16x8 na0, na1;
#pragma unroll
            for (int i = 0; i < 8; ++i) {
                na0[i] = (bf16_t)(f[i] * sc);
                na1[i] = (bf16_t)(f[8 + i] * sc);
            }
#pragma unroll
            for (int nt = 0; nt < 4; ++nt) {
                fa[mt][nt] = MFMA16(na0, pf[nt][0], fa[mt][nt]);
                fa[mt][nt] = MFMA16(na1, pf[nt][1], fa[mt][nt]);
            }
        }
        __syncthreads();  // prev phase2 done reading Vt
#pragma unroll
        for (int mt = 0; mt < 4; ++mt)
#pragma unroll
            for (int nt = 0; nt < 4; ++nt) {
                bf16x4 kp;
#pragma unroll
                for (int r = 0; r < 4; ++r)
                    kp[r] = (bf16_t)(fmaxf(fa[mt][nt][r], 0.0f) + 0.1f);
                *(bf16x4*)&KpT[(wave * 64 + nt * 16 + ln) * 72 + mt * 16 + q * 4] = kp;
            }
        // stage V tile transposed: Vt[d][s]
        for (int j = tid; j < 512; j += 256) {
            int s = j >> 3, d0 = (j & 7) * 8;
            bf16x8 v = *(const bf16x8*)&Vh[(size_t)(s0 + s) * 64 + d0];
#pragma unroll
            for (int e = 0; e < 8; ++e) Vt[(d0 + e) * 72 + s] = v[e];
        }
        __syncthreads();
        // phase 2: KV[f][n] += KpT * Vt
#pragma unroll
        for (int ks = 0; ks < 2; ++ks)
#pragma unroll
            for (int mt = 0; mt < 4; ++mt) {
                bf16x8 a = *(const bf16x8*)&KpT[(wave * 64 + mt * 16 + ln) * 72 + ks * 32 + q * 8];
#pragma unroll
                for (int nt = 0; nt < 5; ++nt) {
                    bf16x8 bb = *(const bf16x8*)&Vt[(nt * 16 + ln) * 72 + ks * 32 + q * 8];
                    kv[mt][nt] = MFMA16(a, bb, kv[mt][nt]);
                }
            }
    }
    float* Pp = P + (size_t)(bh * 4 + c) * 80 * 256;
#pragma unroll
    for (int mt = 0; mt < 4; ++mt)
#pragma unroll
        for (int nt = 0; nt < 5; ++nt)
            *(f32x4*)&Pp[(size_t)(nt * 16 + ln) * 256 + wave * 64 + mt * 16 + q * 4] = kv[mt][nt];
}

// ---------------------------------------------------------------------------
// Reduce 4 chunk-partials -> KVt[bh][n(80)][f(256)] bf16. grid 5120, 256 thr.
// ---------------------------------------------------------------------------
__global__ __launch_bounds__(256) void kreduce(const float* __restrict__ P, bf16_t* __restrict__ KVt)
{
    size_t i = (size_t)blockIdx.x * 256 + threadIdx.x;
    int bh = (int)(i / (256 * 80));
    const float* p = P + (size_t)bh * 4 * 80 * 256 + (i - (size_t)bh * 80 * 256);
    float s = 0.f;
#pragma unroll
    for (int c = 0; c < 4; ++c) s += p[(size_t)c * 80 * 256];
    KVt[i] = (bf16_t)s;
}

// ---------------------------------------------------------------------------
// Q-side, head-major Q, fused norm: Qp=relu(Qhat*proj^T)+0.1;
// out = (Qp*KV)/max(Qp*Ksum,1e-6). grid (64 bh, 64 s-tiles of 64), 256 thr.
// Barrier-free (wave-private LDS rows).
// ---------------------------------------------------------------------------
__global__ __launch_bounds__(256) void qside(
    const bf16_t* __restrict__ Qhm, const bf16_t* __restrict__ proj,
    const bf16_t* __restrict__ KVt, bf16_t* __restrict__ attn)
{
    __shared__ bf16_t Qp[64 * 136];  // [s][f-half], wave-private 16-row slices
    const int tid = threadIdx.x;
    const int lane = tid & 63, wave = tid >> 6;
    const int q = lane >> 4, ln = lane & 15;
    const int bh = blockIdx.x, stile = blockIdx.y;

    const bf16_t* Qh = Qhm + (size_t)bh * 262144 + (size_t)stile * 64 * 64;
    const bf16_t* pr = proj + (size_t)(bh & 15) * 16384;
    const bf16_t* kv = KVt + (size_t)bh * 20480;

    // load A-frags (16 rows/wave) + fused fp32 norm
    const bf16_t* rp = &Qh[(size_t)(wave * 16 + ln) * 64 + q * 8];
    bf16x8 a0 = *(const bf16x8*)rp;
    bf16x8 a1 = *(const bf16x8*)(rp + 32);
    float f[16], ss = 0.f;
#pragma unroll
    for (int i = 0; i < 8; ++i) { f[i] = (float)a0[i]; f[8 + i] = (float)a1[i]; }
#pragma unroll
    for (int i = 0; i < 16; ++i) ss += f[i] * f[i];
    ss += __shfl_xor(ss, 16, 64);
    ss += __shfl_xor(ss, 32, 64);
    float sc = 1.0f / (sqrtf(ss) + 1e-8f);
    bf16x8 na0, na1;
#pragma unroll
    for (int i = 0; i < 8; ++i) {
        na0[i] = (bf16_t)(f[i] * sc);
        na1[i] = (bf16_t)(f[8 + i] * sc);
    }

    f32x4 oacc[5] = {};
#pragma unroll
    for (int fh = 0; fh < 2; ++fh) {
        f32x4 fa[8] = {};
#pragma unroll
        for (int ks = 0; ks < 2; ++ks) {
            bf16x8 bb[8];
#pragma unroll
            for (int nt = 0; nt < 8; ++nt)
                bb[nt] = *(const bf16x8*)&pr[(size_t)(fh * 128 + nt * 16 + ln) * 64 + ks * 32 + q * 8];
            bf16x8 a = ks ? na1 : na0;
#pragma unroll
            for (int nt = 0; nt < 8; ++nt)
                fa[nt] = MFMA16(a, bb[nt], fa[nt]);
        }
#pragma unroll
        for (int nt = 0; nt < 8; ++nt)
#pragma unroll
            for (int r = 0; r < 4; ++r)
                Qp[(wave * 16 + q * 4 + r) * 136 + nt * 16 + ln] =
                    (bf16_t)(fmaxf(fa[nt][r], 0.0f) + 0.1f);
#pragma unroll
        for (int ks = 0; ks < 4; ++ks) {
            bf16x8 aa = *(const bf16x8*)&Qp[(wave * 16 + ln) * 136 + ks * 32 + q * 8];
#pragma unroll
            for (int nt = 0; nt < 5; ++nt) {
                bf16x8 bb = *(const bf16x8*)&kv[(size_t)(nt * 16 + ln) * 256 + fh * 128 + ks * 32 + q * 8];
                oacc[nt] = MFMA16(aa, bb, oacc[nt]);
            }
        }
    }
    bf16_t* Ap = attn + (size_t)bh * 262144 + (size_t)stile * 64 * 64;
#pragma unroll
    for (int r = 0; r < 4; ++r) {
        float nrm = fmaxf(__shfl(oacc[4][r], lane & 48, 64), 1e-6f);
        int sl = wave * 16 + q * 4 + r;
#pragma unroll
        for (int nt = 0; nt < 4; ++nt)
            Ap[(size_t)sl * 64 + nt * 16 + ln] = (bf16_t)(oacc[nt][r] / nrm);
    }
}

// ---------------------------------------------------------------------------
extern "C" void kernel_launch(void* const* d_in, const int* in_sizes, int n_in,
                              void* d_out, int out_size, void* d_ws, size_t ws_size,
                              hipStream_t stream)
{
    const float* x = (const float*)d_in[0];
    const float* Wq = (const float*)d_in[1];
    const float* bq = (const float*)d_in[2];
    const float* Wk = (const float*)d_in[3];
    const float* bk = (const float*)d_in[4];
    const float* Wv = (const float*)d_in[5];
    const float* bv = (const float*)d_in[6];
    const float* Wo = (const float*)d_in[7];
    const float* bo = (const float*)d_in[8];
    const float* proj = (const float*)d_in[9];

    char* ws = (char*)d_ws;
    bf16_t* WT = (bf16_t*)(ws);                      //  8 MiB (4x 1024^2)
    bf16_t* projb = (bf16_t*)(ws + (8ull << 20));    //  0.5 MiB
    bf16_t* KVt = (bf16_t*)(ws + (9ull << 20));      //  2.5 MiB
    bf16_t* Q = (bf16_t*)(ws + (12ull << 20));       // 32 MiB \ contiguous
    bf16_t* K = (bf16_t*)(ws + (44ull << 20));       // 32 MiB | QKV slab
    bf16_t* V = (bf16_t*)(ws + (76ull << 20));       // 32 MiB / (attn reuses V)
    bf16_t* xb = (bf16_t*)(ws + (108ull << 20));     // 32 MiB (P reuses)
    float* P = (float*)xb;                           // 20 MiB, xb dead by then
    bf16_t* attn = V;
    float* out = (float*)d_out;

    castbf<<<8192, 256, 0, stream>>>(x, xb);
    castbf<<<128, 256, 0, stream>>>(proj, projb);
    ktrans<<<dim3(16, 16, 4), 256, 0, stream>>>(Wq, Wk, Wv, Wo, WT);
    // fused QKV GEMM: N=3072, head-major split store into Q/K/V slab
    gemm_bt<0, 2, bf16_t><<<dim3(128, 24), 256, 0, stream>>>(
        xb, WT, bq, bk, bv, Q, 16384, 3072, 1024);
    kside<<<dim3(64, 4), 256, 0, stream>>>(K, V, projb, P);
    kreduce<<<5120, 256, 0, stream>>>(P, KVt);
    qside<<<dim3(64, 64), 256, 0, stream>>>(Q, projb, KVt, attn);
    // final GEMM: A = attn head-major, C = row-major fp32 out
    gemm_bt<1, 0, float><<<dim3(128, 8), 256, 0, stream>>>(
        attn, WT + 3ull * 1048576, bo, bo, bo, out, 16384, 1024, 1024);
}

// Round 4
// 519.720 us; speedup vs baseline: 1.0502x; 1.0502x over previous
//
#include <hip/hip_runtime.h>
#include <stdint.h>

typedef __bf16 bf16_t;
typedef __bf16 bf16x4 __attribute__((ext_vector_type(4)));
typedef __bf16 bf16x8 __attribute__((ext_vector_type(8)));
typedef float  f32x4  __attribute__((ext_vector_type(4)));

typedef __attribute__((address_space(1))) const uint32_t gas_u32;
typedef __attribute__((address_space(3))) uint32_t las_u32;

#define MFMA16(a, b, c) __builtin_amdgcn_mfma_f32_16x16x32_bf16((a), (b), (c), 0, 0, 0)

__device__ __forceinline__ void gl_lds16(const bf16_t* g, bf16_t* l) {
    __builtin_amdgcn_global_load_lds((gas_u32*)g, (las_u32*)l, 16, 0, 0);
}

// ---------------------------------------------------------------------------
// fp32 -> bf16 elementwise cast, 8 elem/thread.
// ---------------------------------------------------------------------------
__global__ __launch_bounds__(256) void castbf(const float* __restrict__ X,
                                              bf16_t* __restrict__ Xb)
{
    size_t i = ((size_t)blockIdx.x * 256 + threadIdx.x) * 8;
    float4 a = *(const float4*)&X[i];
    float4 b = *(const float4*)&X[i + 4];
    bf16x8 o;
    o[0] = (bf16_t)a.x; o[1] = (bf16_t)a.y; o[2] = (bf16_t)a.z; o[3] = (bf16_t)a.w;
    o[4] = (bf16_t)b.x; o[5] = (bf16_t)b.y; o[6] = (bf16_t)b.z; o[7] = (bf16_t)b.w;
    *(bf16x8*)&Xb[i] = o;
}

// ---------------------------------------------------------------------------
// Transpose+cast 1024x1024 fp32 weights -> bf16: O[c][r] = W[r][c].
// grid (16,16,4), 256 thr. WT rows 0..1023=WqT, ..2047=WkT, ..3071=WvT, ..=WoT
// ---------------------------------------------------------------------------
__global__ __launch_bounds__(256) void ktrans(
    const float* __restrict__ W0, const float* __restrict__ W1,
    const float* __restrict__ W2, const float* __restrict__ W3,
    bf16_t* __restrict__ WT)
{
    __shared__ float t[64 * 68];
    const int z = blockIdx.z;
    const float* W = (z == 0) ? W0 : (z == 1) ? W1 : (z == 2) ? W2 : W3;
    bf16_t* O = WT + (size_t)z * 1024 * 1024;
    const int r0 = blockIdx.y * 64, c0 = blockIdx.x * 64;
    const int tid = threadIdx.x;
    const int row = tid >> 2, colg = (tid & 3) * 16;
#pragma unroll
    for (int p = 0; p < 4; ++p)
        *(float4*)&t[row * 68 + colg + p * 4] =
            *(const float4*)&W[(size_t)(r0 + row) * 1024 + c0 + colg + p * 4];
    __syncthreads();
    bf16x8 v0, v1;
#pragma unroll
    for (int j = 0; j < 8; ++j) {
        v0[j] = (bf16_t)t[(colg + j) * 68 + row];
        v1[j] = (bf16_t)t[(colg + 8 + j) * 68 + row];
    }
    *(bf16x8*)&O[(size_t)(c0 + row) * 1024 + r0 + colg] = v0;
    *(bf16x8*)&O[(size_t)(c0 + row) * 1024 + r0 + colg + 8] = v1;
}

// ---------------------------------------------------------------------------
// C = A(MxK) * Bt(NxK)^T + bias, bf16 in, fp32 accum. m97 K-loop.
// CMODE 0: row-major fp32 C[m*N+n] (+bias b0[n]), LDS-vectorized stores.
// CMODE 2: QKV head-major bf16: t=n>>10 -> {Q,K,V} slab (stride 16M elem),
//          h=(n>>6)&15, d=n&63; bias {b0,b1,b2}[t][n&1023]. Wave tile = one
//          head's contiguous 64x64 block -> LDS-staged dwordx4 stores.
// ---------------------------------------------------------------------------
template <int CMODE, typename OutT>
__global__ __launch_bounds__(256) void gemm_bt(
    const bf16_t* __restrict__ A, const bf16_t* __restrict__ Bt,
    const float* __restrict__ b0, const float* __restrict__ b1,
    const float* __restrict__ b2, OutT* __restrict__ C,
    int M, int N, int K)
{
    __shared__ bf16_t As[128 * 32];
    __shared__ bf16_t Bs[128 * 32];
    __shared__ bf16_t Cs[4][32 * 72];  // wave-private epilogue staging (+8 pad)
    const int tid = threadIdx.x;
    const int lane = tid & 63, wave = tid >> 6;
    const int q = lane >> 4, ln = lane & 15;
    const int m0 = blockIdx.x * 128, n0 = blockIdx.y * 128;
    const int wm = (wave >> 1) * 64, wn = (wave & 1) * 64;
    const int srow = tid >> 2, scol = (tid & 3) * 8;

    f32x4 acc[4][4] = {};
    const bf16_t* Ag = A + (size_t)(m0 + srow) * K + scol;
    const bf16_t* Bg = Bt + (size_t)(n0 + srow) * K + scol;
    bf16_t* Al = As + srow * 32 + scol;
    bf16_t* Bl = Bs + srow * 32 + scol;

    for (int k0 = 0; k0 < K; k0 += 32) {
        __syncthreads();
        gl_lds16(Ag + k0, Al);
        gl_lds16(Ag + k0 + (size_t)64 * K, Al + 64 * 32);
        gl_lds16(Bg + k0, Bl);
        gl_lds16(Bg + k0 + (size_t)64 * K, Bl + 64 * 32);
        __syncthreads();
        bf16x8 a[4], b[4];
#pragma unroll
        for (int mt = 0; mt < 4; ++mt)
            a[mt] = *(const bf16x8*)&As[(wm + mt * 16 + ln) * 32 + q * 8];
#pragma unroll
        for (int nt = 0; nt < 4; ++nt)
            b[nt] = *(const bf16x8*)&Bs[(wn + nt * 16 + ln) * 32 + q * 8];
#pragma unroll
        for (int mt = 0; mt < 4; ++mt)
#pragma unroll
            for (int nt = 0; nt < 4; ++nt)
                acc[mt][nt] = MFMA16(a[mt], b[nt], acc[mt][nt]);
    }

    if (CMODE == 0) {
        // fp32 row-major, 4 passes of 16 rows through LDS -> dwordx4 stores
        float* myCf = (float*)&Cs[wave][0];  // 16 x 68 floats = 4352 B
#pragma unroll
        for (int p = 0; p < 4; ++p) {
#pragma unroll
            for (int nt = 0; nt < 4; ++nt) {
                float bv = b0[n0 + wn + nt * 16 + ln];
#pragma unroll
                for (int r = 0; r < 4; ++r)
                    myCf[(q * 4 + r) * 68 + nt * 16 + ln] = acc[p][nt][r] + bv;
            }
#pragma unroll
            for (int c = 0; c < 4; ++c) {
                int flat = c * 64 + lane;
                int rr = flat >> 4, co = (flat & 15) * 4;
                f32x4 v = *(const f32x4*)&myCf[rr * 68 + co];
                *(f32x4*)&C[(size_t)(m0 + wm + p * 16 + rr) * N + n0 + wn + co] = v;
            }
        }
    } else {
        // head-major bf16: wave tile = 64 s-rows x 64 d (one head), contiguous
        const int n_first = n0 + wn;
        const int t = n_first >> 10;
        const int h = (n_first >> 6) & 15;
        const float* bp = (t == 0) ? b0 : (t == 1) ? b1 : b2;
        const int m = m0 + wm;
        const int bI = m >> 12, s0 = m & 4095;
        bf16_t* Cp = (bf16_t*)C + (size_t)t * 16777216 + (size_t)(bI * 16 + h) * 262144;
        bf16_t* myCs = &Cs[wave][0];
#pragma unroll
        for (int p = 0; p < 2; ++p) {
#pragma unroll
            for (int mh = 0; mh < 2; ++mh) {
                int mt = p * 2 + mh;
#pragma unroll
                for (int nt = 0; nt < 4; ++nt) {
                    float bv = bp[(n_first + nt * 16 + ln) & 1023];
#pragma unroll
                    for (int r = 0; r < 4; ++r)
                        myCs[(mh * 16 + q * 4 + r) * 72 + nt * 16 + ln] =
                            (bf16_t)(acc[mt][nt][r] + bv);
                }
            }
#pragma unroll
            for (int c = 0; c < 4; ++c) {
                int flat = c * 64 + lane;
                int rr = flat >> 3, co = (flat & 7) * 8;
                bf16x8 v = *(const bf16x8*)&myCs[rr * 72 + co];
                *(bf16x8*)&Cp[(size_t)(s0 + p * 32 + rr) * 64 + co] = v;
            }
        }
    }
}

// ---------------------------------------------------------------------------
// K-side, head-major K/V, fused L2-norm. Kp=relu(Khat*proj^T)+0.1;
// partial KV[f][n] per s-chunk of 512. grid (64 bh, 8), 256 thr.
// P[bh][c][n(65)][f(256)] fp32. n: 0..63=d, 64=Ksum.
// ---------------------------------------------------------------------------
__global__ __launch_bounds__(256) void kside(
    const bf16_t* __restrict__ Khm, const bf16_t* __restrict__ Vhm,
    const bf16_t* __restrict__ proj, float* __restrict__ P)
{
    __shared__ bf16_t KpT[256 * 72];  // [f][s], wave-private f-slices
    __shared__ bf16_t Vt[80 * 72];    // [n][s], shared
    const int tid = threadIdx.x;
    const int lane = tid & 63, wave = tid >> 6;
    const int q = lane >> 4, ln = lane & 15;
    const int bh = blockIdx.x, c = blockIdx.y;

    const bf16_t* Kh = Khm + (size_t)bh * 262144;
    const bf16_t* Vh = Vhm + (size_t)bh * 262144;
    const bf16_t* pr = proj + (size_t)(bh & 15) * 16384;

    for (int i = tid; i < 16 * 72; i += 256) {
        int rr = i / 72, cc = i % 72;
        Vt[(64 + rr) * 72 + cc] = (rr == 0) ? (bf16_t)1.0f : (bf16_t)0.0f;
    }
    bf16x8 pf[4][2];
#pragma unroll
    for (int nt = 0; nt < 4; ++nt)
#pragma unroll
        for (int ks = 0; ks < 2; ++ks)
            pf[nt][ks] = *(const bf16x8*)&pr[(size_t)(wave * 64 + nt * 16 + ln) * 64 + ks * 32 + q * 8];

    f32x4 kv[4][5] = {};
    const int s_base = c * 512;
    for (int st = 0; st < 8; ++st) {
        const int s0 = s_base + st * 64;
        // phase 1: fused norm + features (64 s x this wave's 64 f)
        f32x4 fa[4][4] = {};
#pragma unroll
        for (int mt = 0; mt < 4; ++mt) {
            const bf16_t* rp = &Kh[(size_t)(s0 + mt * 16 + ln) * 64 + q * 8];
            bf16x8 a0 = *(const bf16x8*)rp;
            bf16x8 a1 = *(const bf16x8*)(rp + 32);
            float f[16], ss = 0.f;
#pragma unroll
            for (int i = 0; i < 8; ++i) { f[i] = (float)a0[i]; f[8 + i] = (float)a1[i]; }
#pragma unroll
            for (int i = 0; i < 16; ++i) ss += f[i] * f[i];
            ss += __shfl_xor(ss, 16, 64);
            ss += __shfl_xor(ss, 32, 64);
            float sc = 1.0f / (sqrtf(ss) + 1e-8f);
            bf16x8 na0, na1;
#pragma unroll
            for (int i = 0; i < 8; ++i) {
                na0[i] = (bf16_t)(f[i] * sc);
                na1[i] = (bf16_t)(f[8 + i] * sc);
            }
#pragma unroll
            for (int nt = 0; nt < 4; ++nt) {
                fa[mt][nt] = MFMA16(na0, pf[nt][0], fa[mt][nt]);
                fa[mt][nt] = MFMA16(na1, pf[nt][1], fa[mt][nt]);
            }
        }
        __syncthreads();  // prev phase2 done reading Vt
#pragma unroll
        for (int mt = 0; mt < 4; ++mt)
#pragma unroll
            for (int nt = 0; nt < 4; ++nt) {
                bf16x4 kp;
#pragma unroll
                for (int r = 0; r < 4; ++r)
                    kp[r] = (bf16_t)(fmaxf(fa[mt][nt][r], 0.0f) + 0.1f);
                *(bf16x4*)&KpT[(wave * 64 + nt * 16 + ln) * 72 + mt * 16 + q * 4] = kp;
            }
        // stage V tile transposed: Vt[d][s]
        for (int j = tid; j < 512; j += 256) {
            int s = j >> 3, d0 = (j & 7) * 8;
            bf16x8 v = *(const bf16x8*)&Vh[(size_t)(s0 + s) * 64 + d0];
#pragma unroll
            for (int e = 0; e < 8; ++e) Vt[(d0 + e) * 72 + s] = v[e];
        }
        __syncthreads();
        // phase 2: KV[f][n] += KpT * Vt
#pragma unroll
        for (int ks = 0; ks < 2; ++ks)
#pragma unroll
            for (int mt = 0; mt < 4; ++mt) {
                bf16x8 a = *(const bf16x8*)&KpT[(wave * 64 + mt * 16 + ln) * 72 + ks * 32 + q * 8];
#pragma unroll
                for (int nt = 0; nt < 5; ++nt) {
                    bf16x8 bb = *(const bf16x8*)&Vt[(nt * 16 + ln) * 72 + ks * 32 + q * 8];
                    kv[mt][nt] = MFMA16(a, bb, kv[mt][nt]);
                }
            }
    }
    float* Pp = P + (size_t)(bh * 8 + c) * 65 * 256;
#pragma unroll
    for (int mt = 0; mt < 4; ++mt)
#pragma unroll
        for (int nt = 0; nt < 5; ++nt)
            if (nt < 4 || ln == 0)
                *(f32x4*)&Pp[(size_t)(nt * 16 + ln) * 256 + wave * 64 + mt * 16 + q * 4] = kv[mt][nt];
}

// ---------------------------------------------------------------------------
// Reduce 8 chunk-partials -> KVt[bh][n(80)][f(256)] bf16 (rows 65..79 = 0).
// grid 5120, 256 thr.
// ---------------------------------------------------------------------------
__global__ __launch_bounds__(256) void kreduce(const float* __restrict__ P, bf16_t* __restrict__ KVt)
{
    size_t i = (size_t)blockIdx.x * 256 + threadIdx.x;
    int f = (int)(i & 255);
    int n = (int)((i >> 8) % 80);
    int bh = (int)(i / (256 * 80));
    float s = 0.f;
    if (n < 65) {
        const float* p = P + (size_t)bh * 8 * 65 * 256 + (size_t)n * 256 + f;
#pragma unroll
        for (int c = 0; c < 8; ++c) s += p[(size_t)c * 65 * 256];
    }
    KVt[i] = (bf16_t)s;
}

// ---------------------------------------------------------------------------
// Q-side, head-major Q, fused norm: Qp=relu(Qhat*proj^T)+0.1;
// out = (Qp*KV)/max(Qp*Ksum,1e-6), written ROW-MAJOR [b*4096+s][h*64+d].
// grid (64 bh, 64 s-tiles of 64), 256 thr. Barrier-free.
// ---------------------------------------------------------------------------
__global__ __launch_bounds__(256) void qside(
    const bf16_t* __restrict__ Qhm, const bf16_t* __restrict__ proj,
    const bf16_t* __restrict__ KVt, bf16_t* __restrict__ attn)
{
    __shared__ bf16_t Qp[64 * 136];  // [s][f-half], wave-private 16-row slices
    const int tid = threadIdx.x;
    const int lane = tid & 63, wave = tid >> 6;
    const int q = lane >> 4, ln = lane & 15;
    const int bh = blockIdx.x, stile = blockIdx.y;
    const int bI = bh >> 4, h = bh & 15;

    const bf16_t* Qh = Qhm + (size_t)bh * 262144 + (size_t)stile * 64 * 64;
    const bf16_t* pr = proj + (size_t)h * 16384;
    const bf16_t* kv = KVt + (size_t)bh * 20480;

    // load A-frags (16 rows/wave) + fused fp32 norm
    const bf16_t* rp = &Qh[(size_t)(wave * 16 + ln) * 64 + q * 8];
    bf16x8 a0 = *(const bf16x8*)rp;
    bf16x8 a1 = *(const bf16x8*)(rp + 32);
    float f[16], ss = 0.f;
#pragma unroll
    for (int i = 0; i < 8; ++i) { f[i] = (float)a0[i]; f[8 + i] = (float)a1[i]; }
#pragma unroll
    for (int i = 0; i < 16; ++i) ss += f[i] * f[i];
    ss += __shfl_xor(ss, 16, 64);
    ss += __shfl_xor(ss, 32, 64);
    float sc = 1.0f / (sqrtf(ss) + 1e-8f);
    bf16x8 na0, na1;
#pragma unroll
    for (int i = 0; i < 8; ++i) {
        na0[i] = (bf16_t)(f[i] * sc);
        na1[i] = (bf16_t)(f[8 + i] * sc);
    }

    f32x4 oacc[5] = {};
#pragma unroll
    for (int fh = 0; fh < 2; ++fh) {
        f32x4 fa[8] = {};
#pragma unroll
        for (int ks = 0; ks < 2; ++ks) {
            bf16x8 bb[8];
#pragma unroll
            for (int nt = 0; nt < 8; ++nt)
                bb[nt] = *(const bf16x8*)&pr[(size_t)(fh * 128 + nt * 16 + ln) * 64 + ks * 32 + q * 8];
            bf16x8 a = ks ? na1 : na0;
#pragma unroll
            for (int nt = 0; nt < 8; ++nt)
                fa[nt] = MFMA16(a, bb[nt], fa[nt]);
        }
#pragma unroll
        for (int nt = 0; nt < 8; ++nt)
#pragma unroll
            for (int r = 0; r < 4; ++r)
                Qp[(wave * 16 + q * 4 + r) * 136 + nt * 16 + ln] =
                    (bf16_t)(fmaxf(fa[nt][r], 0.0f) + 0.1f);
#pragma unroll
        for (int ks = 0; ks < 4; ++ks) {
            bf16x8 aa = *(const bf16x8*)&Qp[(wave * 16 + ln) * 136 + ks * 32 + q * 8];
#pragma unroll
            for (int nt = 0; nt < 5; ++nt) {
                bf16x8 bb = *(const bf16x8*)&kv[(size_t)(nt * 16 + ln) * 256 + fh * 128 + ks * 32 + q * 8];
                oacc[nt] = MFMA16(aa, bb, oacc[nt]);
            }
        }
    }
    // row-major attn: [(bI*4096 + s)*1024 + h*64 + d]
    bf16_t* Ap = attn + ((size_t)(bI * 4096 + stile * 64) * 1024) + h * 64;
#pragma unroll
    for (int r = 0; r < 4; ++r) {
        float nrm = fmaxf(__shfl(oacc[4][r], lane & 48, 64), 1e-6f);
        int sl = wave * 16 + q * 4 + r;
#pragma unroll
        for (int nt = 0; nt < 4; ++nt)
            Ap[(size_t)sl * 1024 + nt * 16 + ln] = (bf16_t)(oacc[nt][r] / nrm);
    }
}

// ---------------------------------------------------------------------------
extern "C" void kernel_launch(void* const* d_in, const int* in_sizes, int n_in,
                              void* d_out, int out_size, void* d_ws, size_t ws_size,
                              hipStream_t stream)
{
    const float* x = (const float*)d_in[0];
    const float* Wq = (const float*)d_in[1];
    const float* bq = (const float*)d_in[2];
    const float* Wk = (const float*)d_in[3];
    const float* bk = (const float*)d_in[4];
    const float* Wv = (const float*)d_in[5];
    const float* bv = (const float*)d_in[6];
    const float* Wo = (const float*)d_in[7];
    const float* bo = (const float*)d_in[8];
    const float* proj = (const float*)d_in[9];

    char* ws = (char*)d_ws;
    bf16_t* WT = (bf16_t*)(ws);                      //  8 MiB (4x 1024^2)
    bf16_t* projb = (bf16_t*)(ws + (8ull << 20));    //  0.5 MiB
    bf16_t* KVt = (bf16_t*)(ws + (9ull << 20));      //  2.5 MiB
    bf16_t* Q = (bf16_t*)(ws + (12ull << 20));       // 32 MiB \ contiguous
    bf16_t* K = (bf16_t*)(ws + (44ull << 20));       // 32 MiB | QKV slab
    bf16_t* V = (bf16_t*)(ws + (76ull << 20));       // 32 MiB / (attn reuses V)
    bf16_t* xb = (bf16_t*)(ws + (108ull << 20));     // 32 MiB (P reuses, 32.5MB)
    float* P = (float*)xb;                           // xb dead after QKV GEMM
    bf16_t* attn = V;                                // V dead after kside
    float* out = (float*)d_out;

    castbf<<<8192, 256, 0, stream>>>(x, xb);
    castbf<<<128, 256, 0, stream>>>(proj, projb);
    ktrans<<<dim3(16, 16, 4), 256, 0, stream>>>(Wq, Wk, Wv, Wo, WT);
    // fused QKV GEMM: N=3072, head-major vectorized store into Q/K/V slab
    gemm_bt<2, bf16_t><<<dim3(128, 24), 256, 0, stream>>>(
        xb, WT, bq, bk, bv, Q, 16384, 3072, 1024);
    kside<<<dim3(64, 8), 256, 0, stream>>>(K, V, projb, P);
    kreduce<<<5120, 256, 0, stream>>>(P, KVt);
    qside<<<dim3(64, 64), 256, 0, stream>>>(Q, projb, KVt, attn);
    // final GEMM: A = attn row-major, C = row-major fp32 out
    gemm_bt<0, float><<<dim3(128, 8), 256, 0, stream>>>(
        attn, WT + 3ull * 1048576, bo, bo, bo, out, 16384, 1024, 1024);
}

// Round 5
// 467.356 us; speedup vs baseline: 1.1678x; 1.1120x over previous
//
#include <hip/hip_runtime.h>
#include <stdint.h>

typedef __bf16 bf16_t;
typedef __bf16 bf16x4 __attribute__((ext_vector_type(4)));
typedef __bf16 bf16x8 __attribute__((ext_vector_type(8)));
typedef float  f32x4  __attribute__((ext_vector_type(4)));

typedef __attribute__((address_space(1))) const uint32_t gas_u32;
typedef __attribute__((address_space(3))) uint32_t las_u32;

#define MFMA16(a, b, c) __builtin_amdgcn_mfma_f32_16x16x32_bf16((a), (b), (c), 0, 0, 0)

__device__ __forceinline__ void gl_lds16(const bf16_t* g, bf16_t* l) {
    __builtin_amdgcn_global_load_lds((gas_u32*)g, (las_u32*)l, 16, 0, 0);
}

// ---------------------------------------------------------------------------
// fp32 -> bf16 elementwise cast, 8 elem/thread.
// ---------------------------------------------------------------------------
__global__ __launch_bounds__(256) void castbf(const float* __restrict__ X,
                                              bf16_t* __restrict__ Xb)
{
    size_t i = ((size_t)blockIdx.x * 256 + threadIdx.x) * 8;
    float4 a = *(const float4*)&X[i];
    float4 b = *(const float4*)&X[i + 4];
    bf16x8 o;
    o[0] = (bf16_t)a.x; o[1] = (bf16_t)a.y; o[2] = (bf16_t)a.z; o[3] = (bf16_t)a.w;
    o[4] = (bf16_t)b.x; o[5] = (bf16_t)b.y; o[6] = (bf16_t)b.z; o[7] = (bf16_t)b.w;
    *(bf16x8*)&Xb[i] = o;
}

// ---------------------------------------------------------------------------
// Transpose+cast 1024x1024 fp32 weights -> bf16: O[c][r] = W[r][c].
// grid (16,16,4), 256 thr. WT rows 0..1023=WqT, ..2047=WkT, ..3071=WvT, ..=WoT
// ---------------------------------------------------------------------------
__global__ __launch_bounds__(256) void ktrans(
    const float* __restrict__ W0, const float* __restrict__ W1,
    const float* __restrict__ W2, const float* __restrict__ W3,
    bf16_t* __restrict__ WT)
{
    __shared__ float t[64 * 68];
    const int z = blockIdx.z;
    const float* W = (z == 0) ? W0 : (z == 1) ? W1 : (z == 2) ? W2 : W3;
    bf16_t* O = WT + (size_t)z * 1024 * 1024;
    const int r0 = blockIdx.y * 64, c0 = blockIdx.x * 64;
    const int tid = threadIdx.x;
    const int row = tid >> 2, colg = (tid & 3) * 16;
#pragma unroll
    for (int p = 0; p < 4; ++p)
        *(float4*)&t[row * 68 + colg + p * 4] =
            *(const float4*)&W[(size_t)(r0 + row) * 1024 + c0 + colg + p * 4];
    __syncthreads();
    bf16x8 v0, v1;
#pragma unroll
    for (int j = 0; j < 8; ++j) {
        v0[j] = (bf16_t)t[(colg + j) * 68 + row];
        v1[j] = (bf16_t)t[(colg + 8 + j) * 68 + row];
    }
    *(bf16x8*)&O[(size_t)(c0 + row) * 1024 + r0 + colg] = v0;
    *(bf16x8*)&O[(size_t)(c0 + row) * 1024 + r0 + colg + 8] = v1;
}

// ---------------------------------------------------------------------------
// C = A(MxK) * Bt(NxK)^T + bias, bf16 in, fp32 accum. m97 K-loop.
// CMODE 0: row-major fp32 C[m*N+n] (+bias b0[n]), LDS-vectorized stores.
// CMODE 2: QKV head-major bf16: t=n>>10 -> {Q,K,V} slab (stride 16M elem),
//          h=(n>>6)&15, d=n&63; bias {b0,b1,b2}[t][n&1023]. Wave tile = one
//          head's contiguous 64x64 block -> LDS-staged dwordx4 stores.
// ---------------------------------------------------------------------------
template <int CMODE, typename OutT>
__global__ __launch_bounds__(256) void gemm_bt(
    const bf16_t* __restrict__ A, const bf16_t* __restrict__ Bt,
    const float* __restrict__ b0, const float* __restrict__ b1,
    const float* __restrict__ b2, OutT* __restrict__ C,
    int M, int N, int K)
{
    __shared__ bf16_t As[128 * 32];
    __shared__ bf16_t Bs[128 * 32];
    __shared__ bf16_t Cs[4][32 * 72];  // wave-private epilogue staging (+8 pad)
    const int tid = threadIdx.x;
    const int lane = tid & 63, wave = tid >> 6;
    const int q = lane >> 4, ln = lane & 15;
    const int m0 = blockIdx.x * 128, n0 = blockIdx.y * 128;
    const int wm = (wave >> 1) * 64, wn = (wave & 1) * 64;
    const int srow = tid >> 2, scol = (tid & 3) * 8;

    f32x4 acc[4][4] = {};
    const bf16_t* Ag = A + (size_t)(m0 + srow) * K + scol;
    const bf16_t* Bg = Bt + (size_t)(n0 + srow) * K + scol;
    bf16_t* Al = As + srow * 32 + scol;
    bf16_t* Bl = Bs + srow * 32 + scol;

    for (int k0 = 0; k0 < K; k0 += 32) {
        __syncthreads();
        gl_lds16(Ag + k0, Al);
        gl_lds16(Ag + k0 + (size_t)64 * K, Al + 64 * 32);
        gl_lds16(Bg + k0, Bl);
        gl_lds16(Bg + k0 + (size_t)64 * K, Bl + 64 * 32);
        __syncthreads();
        bf16x8 a[4], b[4];
#pragma unroll
        for (int mt = 0; mt < 4; ++mt)
            a[mt] = *(const bf16x8*)&As[(wm + mt * 16 + ln) * 32 + q * 8];
#pragma unroll
        for (int nt = 0; nt < 4; ++nt)
            b[nt] = *(const bf16x8*)&Bs[(wn + nt * 16 + ln) * 32 + q * 8];
#pragma unroll
        for (int mt = 0; mt < 4; ++mt)
#pragma unroll
            for (int nt = 0; nt < 4; ++nt)
                acc[mt][nt] = MFMA16(a[mt], b[nt], acc[mt][nt]);
    }

    if (CMODE == 0) {
        // fp32 row-major, 4 passes of 16 rows through LDS -> dwordx4 stores
        float* myCf = (float*)&Cs[wave][0];  // 16 x 68 floats = 4352 B
#pragma unroll
        for (int p = 0; p < 4; ++p) {
#pragma unroll
            for (int nt = 0; nt < 4; ++nt) {
                float bv = b0[n0 + wn + nt * 16 + ln];
#pragma unroll
                for (int r = 0; r < 4; ++r)
                    myCf[(q * 4 + r) * 68 + nt * 16 + ln] = acc[p][nt][r] + bv;
            }
#pragma unroll
            for (int c = 0; c < 4; ++c) {
                int flat = c * 64 + lane;
                int rr = flat >> 4, co = (flat & 15) * 4;
                f32x4 v = *(const f32x4*)&myCf[rr * 68 + co];
                *(f32x4*)&C[(size_t)(m0 + wm + p * 16 + rr) * N + n0 + wn + co] = v;
            }
        }
    } else {
        // head-major bf16: wave tile = 64 s-rows x 64 d (one head), contiguous
        const int n_first = n0 + wn;
        const int t = n_first >> 10;
        const int h = (n_first >> 6) & 15;
        const float* bp = (t == 0) ? b0 : (t == 1) ? b1 : b2;
        const int m = m0 + wm;
        const int bI = m >> 12, s0 = m & 4095;
        bf16_t* Cp = (bf16_t*)C + (size_t)t * 16777216 + (size_t)(bI * 16 + h) * 262144;
        bf16_t* myCs = &Cs[wave][0];
#pragma unroll
        for (int p = 0; p < 2; ++p) {
#pragma unroll
            for (int mh = 0; mh < 2; ++mh) {
                int mt = p * 2 + mh;
#pragma unroll
                for (int nt = 0; nt < 4; ++nt) {
                    float bv = bp[(n_first + nt * 16 + ln) & 1023];
#pragma unroll
                    for (int r = 0; r < 4; ++r)
                        myCs[(mh * 16 + q * 4 + r) * 72 + nt * 16 + ln] =
                            (bf16_t)(acc[mt][nt][r] + bv);
                }
            }
#pragma unroll
            for (int c = 0; c < 4; ++c) {
                int flat = c * 64 + lane;
                int rr = flat >> 3, co = (flat & 7) * 8;
                bf16x8 v = *(const bf16x8*)&myCs[rr * 72 + co];
                *(bf16x8*)&Cp[(size_t)(s0 + p * 32 + rr) * 64 + co] = v;
            }
        }
    }
}

// ---------------------------------------------------------------------------
// K-side, head-major K/V, fused L2-norm. Kp=relu(Khat*proj^T)+0.1;
// partial KV[f][n] per s-chunk of 512. grid (64 bh, 8), 256 thr.
// P[bh][c][n(65)][f(256)] fp32. n: 0..63=d, 64=Ksum.
// ---------------------------------------------------------------------------
__global__ __launch_bounds__(256) void kside(
    const bf16_t* __restrict__ Khm, const bf16_t* __restrict__ Vhm,
    const bf16_t* __restrict__ proj, float* __restrict__ P)
{
    __shared__ bf16_t KpT[256 * 72];  // [f][s], wave-private f-slices
    __shared__ bf16_t Vt[80 * 72];    // [n][s], shared
    const int tid = threadIdx.x;
    const int lane = tid & 63, wave = tid >> 6;
    const int q = lane >> 4, ln = lane & 15;
    const int bh = blockIdx.x, c = blockIdx.y;

    const bf16_t* Kh = Khm + (size_t)bh * 262144;
    const bf16_t* Vh = Vhm + (size_t)bh * 262144;
    const bf16_t* pr = proj + (size_t)(bh & 15) * 16384;

    for (int i = tid; i < 16 * 72; i += 256) {
        int rr = i / 72, cc = i % 72;
        Vt[(64 + rr) * 72 + cc] = (rr == 0) ? (bf16_t)1.0f : (bf16_t)0.0f;
    }
    bf16x8 pf[4][2];
#pragma unroll
    for (int nt = 0; nt < 4; ++nt)
#pragma unroll
        for (int ks = 0; ks < 2; ++ks)
            pf[nt][ks] = *(const bf16x8*)&pr[(size_t)(wave * 64 + nt * 16 + ln) * 64 + ks * 32 + q * 8];

    f32x4 kv[4][5] = {};
    const int s_base = c * 512;
    for (int st = 0; st < 8; ++st) {
        const int s0 = s_base + st * 64;
        // phase 1: fused norm + features (64 s x this wave's 64 f)
        f32x4 fa[4][4] = {};
#pragma unroll
        for (int mt = 0; mt < 4; ++mt) {
            const bf16_t* rp = &Kh[(size_t)(s0 + mt * 16 + ln) * 64 + q * 8];
            bf16x8 a0 = *(const bf16x8*)rp;
            bf16x8 a1 = *(const bf16x8*)(rp + 32);
            float f[16], ss = 0.f;
#pragma unroll
            for (int i = 0; i < 8; ++i) { f[i] = (float)a0[i]; f[8 + i] = (float)a1[i]; }
#pragma unroll
            for (int i = 0; i < 16; ++i) ss += f[i] * f[i];
            ss += __shfl_xor(ss, 16, 64);
            ss += __shfl_xor(ss, 32, 64);
            float sc = 1.0f / (sqrtf(ss) + 1e-8f);
            bf16x8 na0, na1;
#pragma unroll
            for (int i = 0; i < 8; ++i) {
                na0[i] = (bf16_t)(f[i] * sc);
                na1[i] = (bf16_t)(f[8 + i] * sc);
            }
#pragma unroll
            for (int nt = 0; nt < 4; ++nt) {
                fa[mt][nt] = MFMA16(na0, pf[nt][0], fa[mt][nt]);
                fa[mt][nt] = MFMA16(na1, pf[nt][1], fa[mt][nt]);
            }
        }
        __syncthreads();  // prev phase2 done reading Vt
#pragma unroll
        for (int mt = 0; mt < 4; ++mt)
#pragma unroll
            for (int nt = 0; nt < 4; ++nt) {
                bf16x4 kp;
#pragma unroll
                for (int r = 0; r < 4; ++r)
                    kp[r] = (bf16_t)(fmaxf(fa[mt][nt][r], 0.0f) + 0.1f);
                *(bf16x4*)&KpT[(wave * 64 + nt * 16 + ln) * 72 + mt * 16 + q * 4] = kp;
            }
        // stage V tile transposed: Vt[d][s]
        for (int j = tid; j < 512; j += 256) {
            int s = j >> 3, d0 = (j & 7) * 8;
            bf16x8 v = *(const bf16x8*)&Vh[(size_t)(s0 + s) * 64 + d0];
#pragma unroll
            for (int e = 0; e < 8; ++e) Vt[(d0 + e) * 72 + s] = v[e];
        }
        __syncthreads();
        // phase 2: KV[f][n] += KpT * Vt
#pragma unroll
        for (int ks = 0; ks < 2; ++ks)
#pragma unroll
            for (int mt = 0; mt < 4; ++mt) {
                bf16x8 a = *(const bf16x8*)&KpT[(wave * 64 + mt * 16 + ln) * 72 + ks * 32 + q * 8];
#pragma unroll
                for (int nt = 0; nt < 5; ++nt) {
                    bf16x8 bb = *(const bf16x8*)&Vt[(nt * 16 + ln) * 72 + ks * 32 + q * 8];
                    kv[mt][nt] = MFMA16(a, bb, kv[mt][nt]);
                }
            }
    }
    float* Pp = P + (size_t)(bh * 8 + c) * 65 * 256;
#pragma unroll
    for (int mt = 0; mt < 4; ++mt)
#pragma unroll
        for (int nt = 0; nt < 5; ++nt)
            if (nt < 4 || ln == 0)
                *(f32x4*)&Pp[(size_t)(nt * 16 + ln) * 256 + wave * 64 + mt * 16 + q * 4] = kv[mt][nt];
}

// ---------------------------------------------------------------------------
// Reduce 8 chunk-partials -> KVt[bh][n(80)][f(256)] bf16 (rows 65..79 = 0).
// grid 5120, 256 thr.
// ---------------------------------------------------------------------------
__global__ __launch_bounds__(256) void kreduce(const float* __restrict__ P, bf16_t* __restrict__ KVt)
{
    size_t i = (size_t)blockIdx.x * 256 + threadIdx.x;
    int f = (int)(i & 255);
    int n = (int)((i >> 8) % 80);
    int bh = (int)(i / (256 * 80));
    float s = 0.f;
    if (n < 65) {
        const float* p = P + (size_t)bh * 8 * 65 * 256 + (size_t)n * 256 + f;
#pragma unroll
        for (int c = 0; c < 8; ++c) s += p[(size_t)c * 65 * 256];
    }
    KVt[i] = (bf16_t)s;
}

// ---------------------------------------------------------------------------
// Q-side, head-major Q, fused norm: Qp=relu(Qhat*proj^T)+0.1;
// out = (Qp*KV)/max(Qp*Ksum,1e-6), written ROW-MAJOR [b*4096+s][h*64+d].
// grid (64 bh, 32 s-tiles of 128), 256 thr. FAT waves: 2 m-frags (32 rows)
// per wave -> 2x independent MFMA chains (round-2 structure + coalesced
// loads). Barrier-free: Qp rows are wave-private 32-row bands.
// ---------------------------------------------------------------------------
__global__ __launch_bounds__(256) void qside(
    const bf16_t* __restrict__ Qhm, const bf16_t* __restrict__ proj,
    const bf16_t* __restrict__ KVt, bf16_t* __restrict__ attn)
{
    __shared__ bf16_t Qp[128 * 136];  // [s][f-half], wave-private 32-row bands
    const int tid = threadIdx.x;
    const int lane = tid & 63, wave = tid >> 6;
    const int q = lane >> 4, ln = lane & 15;
    const int bh = blockIdx.x, stile = blockIdx.y;
    const int bI = bh >> 4, h = bh & 15;

    const bf16_t* Qh = Qhm + (size_t)bh * 262144 + (size_t)stile * 128 * 64;
    const bf16_t* pr = proj + (size_t)h * 16384;
    const bf16_t* kv = KVt + (size_t)bh * 20480;

    // load 2 A-frags (32 rows/wave) + fused fp32 norm
    bf16x8 na[2][2];
#pragma unroll
    for (int mt = 0; mt < 2; ++mt) {
        const bf16_t* rp = &Qh[(size_t)(wave * 32 + mt * 16 + ln) * 64 + q * 8];
        bf16x8 a0 = *(const bf16x8*)rp;
        bf16x8 a1 = *(const bf16x8*)(rp + 32);
        float f[16], ss = 0.f;
#pragma unroll
        for (int i = 0; i < 8; ++i) { f[i] = (float)a0[i]; f[8 + i] = (float)a1[i]; }
#pragma unroll
        for (int i = 0; i < 16; ++i) ss += f[i] * f[i];
        ss += __shfl_xor(ss, 16, 64);
        ss += __shfl_xor(ss, 32, 64);
        float sc = 1.0f / (sqrtf(ss) + 1e-8f);
#pragma unroll
        for (int i = 0; i < 8; ++i) {
            na[mt][0][i] = (bf16_t)(f[i] * sc);
            na[mt][1][i] = (bf16_t)(f[8 + i] * sc);
        }
    }

    f32x4 oacc[2][5] = {};
#pragma unroll
    for (int fh = 0; fh < 2; ++fh) {
        f32x4 fa[2][8] = {};
#pragma unroll
        for (int ks = 0; ks < 2; ++ks) {
            bf16x8 bb[8];
#pragma unroll
            for (int nt = 0; nt < 8; ++nt)
                bb[nt] = *(const bf16x8*)&pr[(size_t)(fh * 128 + nt * 16 + ln) * 64 + ks * 32 + q * 8];
#pragma unroll
            for (int mt = 0; mt < 2; ++mt)
#pragma unroll
                for (int nt = 0; nt < 8; ++nt)
                    fa[mt][nt] = MFMA16(na[mt][ks], bb[nt], fa[mt][nt]);
        }
#pragma unroll
        for (int mt = 0; mt < 2; ++mt)
#pragma unroll
            for (int nt = 0; nt < 8; ++nt)
#pragma unroll
                for (int r = 0; r < 4; ++r)
                    Qp[(wave * 32 + mt * 16 + q * 4 + r) * 136 + nt * 16 + ln] =
                        (bf16_t)(fmaxf(fa[mt][nt][r], 0.0f) + 0.1f);
#pragma unroll
        for (int ks = 0; ks < 4; ++ks) {
            bf16x8 aa[2];
#pragma unroll
            for (int mt = 0; mt < 2; ++mt)
                aa[mt] = *(const bf16x8*)&Qp[(wave * 32 + mt * 16 + ln) * 136 + ks * 32 + q * 8];
#pragma unroll
            for (int nt = 0; nt < 5; ++nt) {
                bf16x8 bb = *(const bf16x8*)&kv[(size_t)(nt * 16 + ln) * 256 + fh * 128 + ks * 32 + q * 8];
#pragma unroll
                for (int mt = 0; mt < 2; ++mt)
                    oacc[mt][nt] = MFMA16(aa[mt], bb, oacc[mt][nt]);
            }
        }
    }
    // row-major attn: [(bI*4096 + stile*128 + sl)*1024 + h*64 + d]
    bf16_t* Ap = attn + ((size_t)(bI * 4096 + stile * 128) * 1024) + h * 64;
#pragma unroll
    for (int mt = 0; mt < 2; ++mt)
#pragma unroll
        for (int r = 0; r < 4; ++r) {
            float nrm = fmaxf(__shfl(oacc[mt][4][r], lane & 48, 64), 1e-6f);
            int sl = wave * 32 + mt * 16 + q * 4 + r;
#pragma unroll
            for (int nt = 0; nt < 4; ++nt)
                Ap[(size_t)sl * 1024 + nt * 16 + ln] = (bf16_t)(oacc[mt][nt][r] / nrm);
        }
}

// ---------------------------------------------------------------------------
extern "C" void kernel_launch(void* const* d_in, const int* in_sizes, int n_in,
                              void* d_out, int out_size, void* d_ws, size_t ws_size,
                              hipStream_t stream)
{
    const float* x = (const float*)d_in[0];
    const float* Wq = (const float*)d_in[1];
    const float* bq = (const float*)d_in[2];
    const float* Wk = (const float*)d_in[3];
    const float* bk = (const float*)d_in[4];
    const float* Wv = (const float*)d_in[5];
    const float* bv = (const float*)d_in[6];
    const float* Wo = (const float*)d_in[7];
    const float* bo = (const float*)d_in[8];
    const float* proj = (const float*)d_in[9];

    char* ws = (char*)d_ws;
    bf16_t* WT = (bf16_t*)(ws);                      //  8 MiB (4x 1024^2)
    bf16_t* projb = (bf16_t*)(ws + (8ull << 20));    //  0.5 MiB
    bf16_t* KVt = (bf16_t*)(ws + (9ull << 20));      //  2.5 MiB
    bf16_t* Q = (bf16_t*)(ws + (12ull << 20));       // 32 MiB \ contiguous
    bf16_t* K = (bf16_t*)(ws + (44ull << 20));       // 32 MiB | QKV slab
    bf16_t* V = (bf16_t*)(ws + (76ull << 20));       // 32 MiB / (attn reuses V)
    bf16_t* xb = (bf16_t*)(ws + (108ull << 20));     // 32 MiB (P reuses, 32.5MB)
    float* P = (float*)xb;                           // xb dead after QKV GEMM
    bf16_t* attn = V;                                // V dead after kside
    float* out = (float*)d_out;

    castbf<<<8192, 256, 0, stream>>>(x, xb);
    castbf<<<128, 256, 0, stream>>>(proj, projb);
    ktrans<<<dim3(16, 16, 4), 256, 0, stream>>>(Wq, Wk, Wv, Wo, WT);
    // fused QKV GEMM: N=3072, head-major vectorized store into Q/K/V slab
    gemm_bt<2, bf16_t><<<dim3(128, 24), 256, 0, stream>>>(
        xb, WT, bq, bk, bv, Q, 16384, 3072, 1024);
    kside<<<dim3(64, 8), 256, 0, stream>>>(K, V, projb, P);
    kreduce<<<5120, 256, 0, stream>>>(P, KVt);
    qside<<<dim3(64, 32), 256, 0, stream>>>(Q, projb, KVt, attn);
    // final GEMM: A = attn row-major, C = row-major fp32 out
    gemm_bt<0, float><<<dim3(128, 8), 256, 0, stream>>>(
        attn, WT + 3ull * 1048576, bo, bo, bo, out, 16384, 1024, 1024);
}